// Round 1
// 849.219 us; speedup vs baseline: 1.0037x; 1.0037x over previous
//
#include <hip/hip_runtime.h>

namespace {

constexpr int NN = 50000;   // nodes
constexpr int NE = 800000;  // edges
constexpr int NB = 64;      // graphs / batch
constexpr int NL = 32;      // path length
constexpr int ND = 256;     // D == H == 256
constexpr int NSCAN = 196;  // ceil(50176/256) scan blocks

typedef __attribute__((ext_vector_type(8))) short short8v;  // 8 bf16 (4 VGPRs)
typedef __attribute__((ext_vector_type(4))) float float4v;  // MFMA accumulator

// async global->LDS, 16B per lane, linear dest (wave-uniform base + lane*16)
#define GLD16(GP, LP) __builtin_amdgcn_global_load_lds( \
    (const __attribute__((address_space(1))) void*)(GP), \
    (__attribute__((address_space(3))) void*)(LP), 16, 0, 0)

__device__ __forceinline__ float sigf(float x){ return 1.0f/(1.0f + __expf(-x)); }

__device__ __forceinline__ ushort rne_bf16(float f){
  uint u = __float_as_uint(f);
  return (ushort)((u + 0x7FFFu + ((u >> 16) & 1u)) >> 16);
}
__device__ __forceinline__ float bf2f(ushort u){ return __uint_as_float((uint)u << 16); }

// hi = trunc-bf16(f) (exact bits), lo = trunc-bf16(f - hi) — identical math to split8
__device__ __forceinline__ void split1(float f, ushort& h, ushort& lo){
  uint u = __float_as_uint(f);
  h = (ushort)(u >> 16);
  float r = f - __uint_as_float(u & 0xFFFF0000u);
  lo = (ushort)(__float_as_uint(r) >> 16);
}

// split 8 fp32 -> 8 bf16-hi (truncated; exact bits) + 8 bf16-lo (of remainder)
__device__ __forceinline__ void split8(float4 fa, float4 fb, uint4& h, uint4& lo){
  uint a0=__float_as_uint(fa.x), a1=__float_as_uint(fa.y), a2=__float_as_uint(fa.z), a3=__float_as_uint(fa.w);
  uint b0=__float_as_uint(fb.x), b1=__float_as_uint(fb.y), b2=__float_as_uint(fb.z), b3=__float_as_uint(fb.w);
  h.x = (a0>>16) | (a1 & 0xFFFF0000u);
  h.y = (a2>>16) | (a3 & 0xFFFF0000u);
  h.z = (b0>>16) | (b1 & 0xFFFF0000u);
  h.w = (b2>>16) | (b3 & 0xFFFF0000u);
  float r0 = fa.x - __uint_as_float(a0 & 0xFFFF0000u);
  float r1 = fa.y - __uint_as_float(a1 & 0xFFFF0000u);
  float r2 = fa.z - __uint_as_float(a2 & 0xFFFF0000u);
  float r3 = fa.w - __uint_as_float(a3 & 0xFFFF0000u);
  float r4 = fb.x - __uint_as_float(b0 & 0xFFFF0000u);
  float r5 = fb.y - __uint_as_float(b1 & 0xFFFF0000u);
  float r6 = fb.z - __uint_as_float(b2 & 0xFFFF0000u);
  float r7 = fb.w - __uint_as_float(b3 & 0xFFFF0000u);
  lo.x = (__float_as_uint(r0)>>16) | (__float_as_uint(r1) & 0xFFFF0000u);
  lo.y = (__float_as_uint(r2)>>16) | (__float_as_uint(r3) & 0xFFFF0000u);
  lo.z = (__float_as_uint(r4)>>16) | (__float_as_uint(r5) & 0xFFFF0000u);
  lo.w = (__float_as_uint(r6)>>16) | (__float_as_uint(r7) & 0xFFFF0000u);
}

// ================= CSR build (counting sort of edges by dst) =================
__global__ void k_hist(const int* __restrict__ dst, int* __restrict__ cnt){
  int stride = gridDim.x * blockDim.x;
  for (int e = blockIdx.x*blockDim.x + threadIdx.x; e < NE; e += stride)
    atomicAdd(&cnt[dst[e]], 1);
}

__global__ void k_scan_block(const int* __restrict__ cnt, int* __restrict__ offs,
                             int* __restrict__ bsum){
  __shared__ int s[256];
  const int t = threadIdx.x, i = blockIdx.x*256 + t;
  int v = cnt[i];
  s[t] = v; __syncthreads();
  #pragma unroll
  for (int off = 1; off < 256; off <<= 1){
    int x = (t >= off) ? s[t-off] : 0;
    __syncthreads();
    s[t] += x;
    __syncthreads();
  }
  offs[i] = s[t] - v;
  if (t == 255) bsum[blockIdx.x] = s[255];
}

__global__ void k_scan_top(const int* __restrict__ bsum, int* __restrict__ bsum2){
  __shared__ int s[256];
  const int t = threadIdx.x;
  int v = (t < NSCAN) ? bsum[t] : 0;
  s[t] = v; __syncthreads();
  #pragma unroll
  for (int off = 1; off < 256; off <<= 1){
    int x = (t >= off) ? s[t-off] : 0;
    __syncthreads();
    s[t] += x;
    __syncthreads();
  }
  if (t < NSCAN) bsum2[t] = s[t] - v;
}

__global__ void k_scan_add(int* __restrict__ offs, const int* __restrict__ bsum2,
                           int* __restrict__ cursor){
  const int i = blockIdx.x*256 + threadIdx.x;
  int v = offs[i] + bsum2[blockIdx.x];
  offs[i] = v;
  cursor[i] = v;
}

__global__ void k_fill(const int* __restrict__ src, const int* __restrict__ dst,
                       int* __restrict__ cursor, int* __restrict__ csr){
  int stride = gridDim.x * blockDim.x;
  for (int e = blockIdx.x*blockDim.x + threadIdx.x; e < NE; e += stride){
    int d = dst[e];
    int pos = atomicAdd(&cursor[d], 1);
    csr[pos] = src[e];
  }
}

// ================= fp32 -> bf16 (RNE) bulk convert =================
__global__ void k_tobf16(const float* __restrict__ in, ushort* __restrict__ out){
  const int i = blockIdx.x*blockDim.x + threadIdx.x;   // one per 8 elems
  const float4 a = ((const float4*)in)[i*2];
  const float4 b = ((const float4*)in)[i*2+1];
  ushort o[8] = { rne_bf16(a.x), rne_bf16(a.y), rne_bf16(a.z), rne_bf16(a.w),
                  rne_bf16(b.x), rne_bf16(b.y), rne_bf16(b.z), rne_bf16(b.w) };
  ((uint4*)out)[i] = *(uint4*)o;
}

// ================= mean-aggregate gather over bf16 features =================
// Wave per edge-row; fp32 accumulate; output written pre-split hi/lo bf16
// (bit-identical to the old fp32-out + in-GEMM split8 path).
__launch_bounds__(256, 8)
__global__ void k_gather_bf16(const ushort* __restrict__ feat, const int* __restrict__ offs,
                              const int* __restrict__ csr,
                              ushort* __restrict__ outH, ushort* __restrict__ outL){
  __shared__ float4 sp[256];
  const int u = blockIdx.x, t = threadIdx.x;
  const int w = t >> 6, l = t & 63;
  const int beg = offs[u], end = offs[u+1];
  const int lc = l * 4;
  float a0 = 0.f, a1 = 0.f, a2 = 0.f, a3 = 0.f;
  int e = beg + w;
  for (; e + 4 < end; e += 8){
    int s0 = csr[e], s1 = csr[e+4];
    ushort4 v0 = *(const ushort4*)(feat + (long long)s0*ND + lc);
    ushort4 v1 = *(const ushort4*)(feat + (long long)s1*ND + lc);
    a0 += bf2f(v0.x) + bf2f(v1.x);
    a1 += bf2f(v0.y) + bf2f(v1.y);
    a2 += bf2f(v0.z) + bf2f(v1.z);
    a3 += bf2f(v0.w) + bf2f(v1.w);
  }
  if (e < end){
    int s0 = csr[e];
    ushort4 v0 = *(const ushort4*)(feat + (long long)s0*ND + lc);
    a0 += bf2f(v0.x); a1 += bf2f(v0.y); a2 += bf2f(v0.z); a3 += bf2f(v0.w);
  }
  sp[t] = make_float4(a0, a1, a2, a3);
  __syncthreads();
  if (t < 64){
    float4 p0 = sp[t], p1 = sp[64+t], p2 = sp[128+t], p3 = sp[192+t];
    float inv = 1.0f / fmaxf((float)(end - beg), 1.0f);
    float4 r;
    r.x = (p0.x + p1.x + p2.x + p3.x) * inv;
    r.y = (p0.y + p1.y + p2.y + p3.y) * inv;
    r.z = (p0.z + p1.z + p2.z + p3.z) * inv;
    r.w = (p0.w + p1.w + p2.w + p3.w) * inv;
    ushort hh[4], ll[4];
    split1(r.x, hh[0], ll[0]);
    split1(r.y, hh[1], ll[1]);
    split1(r.z, hh[2], ll[2]);
    split1(r.w, hh[3], ll[3]);
    *(ushort4*)(outH + (long long)u*ND + t*4) = *(ushort4*)hh;
    *(ushort4*)(outL + (long long)u*ND + t*4) = *(ushort4*)ll;
  }
}

// ============ weight prep: fragment-linear swizzled [wl; wr] bf16 hi/lo ============
__global__ void k_wsplit(const float* __restrict__ wl, const float* __restrict__ wr,
                         ushort* __restrict__ WtH, ushort* __restrict__ WtL){
  const int k = blockIdx.x;    // 0..511
  const int n = threadIdx.x;   // 0..255
  float v = (k < 256) ? wl[k*256 + n] : wr[(k-256)*256 + n];
  uint u = __float_as_uint(v);
  float r = v - __uint_as_float(u & 0xFFFF0000u);
  const int wc = n >> 6, nt = (n >> 4) & 3, lm = n & 15;
  const int kk = k >> 5, lq = (k >> 3) & 3, j = k & 7;
  const long long idx = (long long)(((wc*4 + nt)*16 + kk)*64 + lq*16 + lm)*8 + j;
  WtH[idx] = (ushort)(u >> 16);
  WtL[idx] = (ushort)(__float_as_uint(r) >> 16);
}

// ============ MFMA SAGE GEMM: LDS-staged A (global_load_lds dbuf), pre-split hi/lo ============
// A1 = pre-split hi/lo bf16 (gather output). A2 = pre-split hi/lo (layer 2) or fp32 (layer 1,
// split after ds_read). B direct from L2 (fragment-linear swizzled). One barrier per K-step.
// Both-sides XOR chunk swizzle keeps ds_read_b128 at 2-way bank conflicts (free).
// Output always pre-split hi/lo bf16 (+ optional RNE bf16 for the gather path).
__launch_bounds__(256, 3)
__global__ void k_gemm_mfma(const ushort* __restrict__ A1H, const ushort* __restrict__ A1L,
                            const ushort* __restrict__ A2H, const ushort* __restrict__ A2L,
                            const float* __restrict__ A2F,
                            const ushort* __restrict__ WtH, const ushort* __restrict__ WtL,
                            const float* __restrict__ bias,
                            ushort* __restrict__ CH, ushort* __restrict__ CL,
                            ushort* __restrict__ Cb, int relu, int a2f32)
{
  __shared__ float eb[16*260];          // 16.64 KB; first 16 KB doubles as staging dbuf
  char* const sm = (char*)eb;

  const int t  = threadIdx.x;
  const int w  = t >> 6;                // wave 0..3
  const int l  = t & 63;                // lane
  const int lm = l & 15;
  const int lq = l >> 4;
  const int m0 = blockIdx.x * 64;

  const uint4* BH4 = (const uint4*)WtH;
  const uint4* BL4 = (const uint4*)WtL;

  const float4v vzero = {0.f, 0.f, 0.f, 0.f};
  float4v acc[4][4];
  #pragma unroll
  for (int i = 0; i < 4; ++i)
    #pragma unroll
    for (int j = 0; j < 4; ++j) acc[i][j] = vzero;

  int bbase[4];
  #pragma unroll
  for (int nt = 0; nt < 4; ++nt) bbase[nt] = (w*4 + nt)*1024 + l;

  const int j0 = w * 2;   // this wave's pair of staging instructions (of 8 per K-step)

  // hi/lo staging: per buf, SH [64 rows][4 chunks of 16B] at +0, SL at +4096.
  // stored[row][c] = global chunk (c ^ ((row>>1)&3))  -> read side uses same XOR.
  auto stageHL = [&](int bb, const ushort* __restrict__ H, const ushort* __restrict__ L, int k0){
    #pragma unroll
    for (int jj = 0; jj < 2; ++jj){
      const int j   = j0 + jj;        // 0..7
      const int arr = j >> 2;         // 0 = hi, 1 = lo
      const int i   = j & 3;          // 1KB instr within array
      const int row = i*16 + (l >> 2);
      int rg = m0 + row; rg = (rg < NN) ? rg : (NN - 1);
      const int g = (l & 3) ^ ((row >> 1) & 3);
      const ushort* srcp = (arr ? L : H) + (long long)rg*ND + k0 + g*8;
      GLD16(srcp, sm + bb + arr*4096 + i*1024);
    }
  };
  // fp32 staging: per buf, S32 [64 rows][8 chunks of 16B] (8 KB).
  // stored[row][c] = global chunk (c ^ (row&7)).
  auto stageF = [&](int bb, int k0){
    #pragma unroll
    for (int jj = 0; jj < 2; ++jj){
      const int j   = j0 + jj;        // 0..7
      const int row = j*8 + (l >> 3);
      int rg = m0 + row; rg = (rg < NN) ? rg : (NN - 1);
      const int g = (l & 7) ^ (row & 7);
      const float* srcp = A2F + (long long)rg*ND + k0 + g*4;
      GLD16(srcp, sm + bb + j*1024);
    }
  };
  auto stage = [&](int bb, int kk){
    if (kk < 8)      stageHL(bb, A1H, A1L, kk*32);
    else if (!a2f32) stageHL(bb, A2H, A2L, (kk - 8)*32);
    else             stageF (bb, (kk - 8)*32);
  };

  stage(0, 0);
  __syncthreads();   // drains vmcnt: buf0 ready

  #pragma unroll
  for (int kk = 0; kk < 16; ++kk){
    const int bb = (kk & 1) * 8192;

    // B fragments for this step (L2-hot, coalesced)
    uint4 bh[4], bl[4];
    #pragma unroll
    for (int nt = 0; nt < 4; ++nt){
      const int idx = bbase[nt] + kk*64;
      bh[nt] = BH4[idx];
      bl[nt] = BL4[idx];
    }

    // issue next A-tile while computing this one
    if (kk < 15) stage(bb ^ 8192, kk + 1);

    // A fragments from LDS
    uint4 ah[4], al[4];
    if (kk < 8 || !a2f32){
      #pragma unroll
      for (int mt = 0; mt < 4; ++mt){
        const int row = mt*16 + lm;
        const int off = bb + row*64 + ((lq ^ ((row >> 1) & 3)) << 4);
        ah[mt] = *(const uint4*)(sm + off);
        al[mt] = *(const uint4*)(sm + 4096 + off);
      }
    } else {
      #pragma unroll
      for (int mt = 0; mt < 4; ++mt){
        const int row = mt*16 + lm;
        const int s = row & 7;
        const float4 fa = *(const float4*)(sm + bb + row*128 + (((2*lq    ) ^ s) << 4));
        const float4 fb = *(const float4*)(sm + bb + row*128 + (((2*lq + 1) ^ s) << 4));
        split8(fa, fb, ah[mt], al[mt]);
      }
    }

    #pragma unroll
    for (int nt = 0; nt < 4; ++nt){
      short8v bhv = *(short8v*)&bh[nt];
      short8v blv = *(short8v*)&bl[nt];
      #pragma unroll
      for (int mt = 0; mt < 4; ++mt){
        short8v ahv = *(short8v*)&ah[mt];
        short8v alv = *(short8v*)&al[mt];
        acc[mt][nt] = __builtin_amdgcn_mfma_f32_16x16x32_bf16(ahv, bhv, acc[mt][nt], 0, 0, 0);
        acc[mt][nt] = __builtin_amdgcn_mfma_f32_16x16x32_bf16(alv, bhv, acc[mt][nt], 0, 0, 0);
        acc[mt][nt] = __builtin_amdgcn_mfma_f32_16x16x32_bf16(ahv, blv, acc[mt][nt], 0, 0, 0);
      }
    }
    __syncthreads();   // next tile drained; this buffer free for overwrite
  }

  // ---- epilogue: LDS transpose per 16-row slab, coalesced hi/lo bf16 stores ----
  float bvv[4];
  #pragma unroll
  for (int nt = 0; nt < 4; ++nt) bvv[nt] = bias[w*64 + nt*16 + lm];

  #pragma unroll
  for (int mt = 0; mt < 4; ++mt){
    #pragma unroll
    for (int nt = 0; nt < 4; ++nt){
      #pragma unroll
      for (int r = 0; r < 4; ++r){
        float v = acc[mt][nt][r] + bvv[nt];
        if (relu) v = fmaxf(v, 0.f);
        eb[(lq*4 + r)*260 + w*64 + nt*16 + lm] = v;   // C/D: col=lane&15, row=quad*4+reg
      }
    }
    __syncthreads();
    #pragma unroll
    for (int i = 0; i < 4; ++i){
      int idx = i*256 + t;           // 0..1023
      int rr  = idx >> 6;            // 0..15
      int c4  = (idx & 63) * 4;      // 0..252
      int grow = m0 + mt*16 + rr;
      if (grow < NN){
        float4 fv = *(float4*)&eb[rr*260 + c4];
        ushort hh[4], ll[4];
        split1(fv.x, hh[0], ll[0]);
        split1(fv.y, hh[1], ll[1]);
        split1(fv.z, hh[2], ll[2]);
        split1(fv.w, hh[3], ll[3]);
        *(ushort4*)(CH + (long long)grow*ND + c4) = *(ushort4*)hh;
        *(ushort4*)(CL + (long long)grow*ND + c4) = *(ushort4*)ll;
        if (Cb){
          ushort ub[4] = { rne_bf16(fv.x), rne_bf16(fv.y), rne_bf16(fv.z), rne_bf16(fv.w) };
          *(ushort4*)(Cb + (long long)grow*ND + c4) = *(ushort4*)ub;
        }
      }
    }
    __syncthreads();
  }
}

// ---------------- LSTM input gates: Xg[i][g] = emb[paths[i]] . w_ih[g] + b_ih[g]+b_hh[g] ----------------
// emb now arrives as hi/lo bf16 pair; reconstruct hi+lo (2^-16 rel err).
__launch_bounds__(256, 3)
__global__ void k_xgate(const ushort* __restrict__ EH, const ushort* __restrict__ EL,
                        const int* __restrict__ paths,
                        const float* __restrict__ w_ih, const float* __restrict__ b_ih,
                        const float* __restrict__ b_hh, float* __restrict__ xg)
{
  __shared__ float As[16][68];
  __shared__ float Ws[16][260];
  const int t  = threadIdx.x;
  const int m0 = blockIdx.x * 64;    // path rows (2048 total)
  const int g0 = blockIdx.y * 256;   // gate cols (1024 total)
  const int rg = t >> 5, cg = t & 31;
  const int sm = t >> 2, sj = (t & 3) * 4;

  float acc[8][8];
  #pragma unroll
  for (int i = 0; i < 8; ++i)
    #pragma unroll
    for (int j = 0; j < 8; ++j) acc[i][j] = 0.f;

  const int node = paths[m0 + sm];
  const ushort* ehrow = EH + (long long)node*ND;
  const ushort* elrow = EL + (long long)node*ND;
  const float* wrow = w_ih + (long long)(g0 + t)*ND;

  for (int k0 = 0; k0 < 256; k0 += 16){
    ushort4 hv = *(const ushort4*)(ehrow + k0 + sj);
    ushort4 lv = *(const ushort4*)(elrow + k0 + sj);
    float av0 = bf2f(hv.x) + bf2f(lv.x);
    float av1 = bf2f(hv.y) + bf2f(lv.y);
    float av2 = bf2f(hv.z) + bf2f(lv.z);
    float av3 = bf2f(hv.w) + bf2f(lv.w);
    float4 q0 = *(const float4*)(wrow + k0 + 0);
    float4 q1 = *(const float4*)(wrow + k0 + 4);
    float4 q2 = *(const float4*)(wrow + k0 + 8);
    float4 q3 = *(const float4*)(wrow + k0 + 12);
    __syncthreads();
    As[sj+0][sm]=av0; As[sj+1][sm]=av1; As[sj+2][sm]=av2; As[sj+3][sm]=av3;
    Ws[ 0][t]=q0.x; Ws[ 1][t]=q0.y; Ws[ 2][t]=q0.z; Ws[ 3][t]=q0.w;
    Ws[ 4][t]=q1.x; Ws[ 5][t]=q1.y; Ws[ 6][t]=q1.z; Ws[ 7][t]=q1.w;
    Ws[ 8][t]=q2.x; Ws[ 9][t]=q2.y; Ws[10][t]=q2.z; Ws[11][t]=q2.w;
    Ws[12][t]=q3.x; Ws[13][t]=q3.y; Ws[14][t]=q3.z; Ws[15][t]=q3.w;
    __syncthreads();
    #pragma unroll
    for (int k = 0; k < 16; ++k){
      float a[8], b[8];
      *(float4*)&a[0] = *(const float4*)&As[k][rg*8];
      *(float4*)&a[4] = *(const float4*)&As[k][rg*8+4];
      *(float4*)&b[0] = *(const float4*)&Ws[k][cg*8];
      *(float4*)&b[4] = *(const float4*)&Ws[k][cg*8+4];
      #pragma unroll
      for (int i = 0; i < 8; ++i)
        #pragma unroll
        for (int j = 0; j < 8; ++j)
          acc[i][j] = fmaf(a[i], b[j], acc[i][j]);
    }
  }

  float bv[8];
  #pragma unroll
  for (int j = 0; j < 8; ++j){ int g = g0 + cg*8 + j; bv[j] = b_ih[g] + b_hh[g]; }
  #pragma unroll
  for (int i = 0; i < 8; ++i){
    int row = m0 + rg*8 + i;
    float o[8];
    #pragma unroll
    for (int j = 0; j < 8; ++j) o[j] = acc[i][j] + bv[j];
    *(float4*)(xg + (long long)row*1024 + g0 + cg*8 + 0) = *(float4*)&o[0];
    *(float4*)(xg + (long long)row*1024 + g0 + cg*8 + 4) = *(float4*)&o[4];
  }
}

// ---------------- one LSTM step (32-launch version; grid.sync measured 5x worse) ----------------
__launch_bounds__(256, 4)
__global__ void k_lstm_step(const float* __restrict__ h_in, float* __restrict__ h_out,
                            float* __restrict__ c_state, const float* __restrict__ xg,
                            const float* __restrict__ w_hh, int tstep)
{
  __shared__ float ws[4*256];
  __shared__ float hs[32*260];
  __shared__ float part[2*128];
  __shared__ float gs[128];
  const int t  = threadIdx.x;
  const int u  = blockIdx.x >> 1;
  const int b0 = (blockIdx.x & 1) * 32;

  {
    int gate = t >> 6, c4 = (t & 63) * 4;
    float4 v = *(const float4*)(w_hh + (long long)(gate*256 + u)*256 + c4);
    *(float4*)&ws[gate*256 + c4] = v;
  }
  #pragma unroll
  for (int i = 0; i < 8; ++i){
    int idx = i*256 + t;
    int b = idx >> 6, c4 = (idx & 63) * 4;
    float4 v = *(const float4*)(h_in + (long long)(b0 + b)*256 + c4);
    *(float4*)&hs[b*260 + c4] = v;
  }
  __syncthreads();

  const int b  = t & 31;
  const int g  = (t >> 5) & 3;
  const int kd = t >> 7;
  float s = 0.f;
  const float* hp = &hs[b*260 + kd*128];
  const float* wp = &ws[g*256 + kd*128];
  #pragma unroll
  for (int k4 = 0; k4 < 32; ++k4){
    float4 h4 = *(const float4*)(hp + k4*4);
    float4 w4 = *(const float4*)(wp + k4*4);
    s += h4.x*w4.x + h4.y*w4.y + h4.z*w4.z + h4.w*w4.w;
  }
  part[kd*128 + b*4 + g] = s;
  __syncthreads();

  if (t < 128){
    int bb = t >> 2, gg = t & 3;
    const float* xp = xg + ((long long)(b0 + bb)*NL + tstep)*1024;
    gs[t] = part[t] + part[128 + t] + xp[gg*256 + u];
  }
  __syncthreads();

  if (t < 32){
    float gi = gs[t*4+0], gf = gs[t*4+1], gG = gs[t*4+2], go = gs[t*4+3];
    int bb = b0 + t;
    float c_old = c_state[bb*256 + u];
    float c_new = sigf(gf)*c_old + sigf(gi)*tanhf(gG);
    c_state[bb*256 + u] = c_new;
    h_out[bb*256 + u] = sigf(go)*tanhf(c_new);
  }
}

// ---------------- global mean pool (hi/lo bf16 input) ----------------
__global__ void k_pool(const ushort* __restrict__ EH, const ushort* __restrict__ EL,
                       const int* __restrict__ batch,
                       float* __restrict__ gsum, float* __restrict__ gcnt)
{
  __shared__ int bs[256];
  const int t  = threadIdx.x;
  const int n0 = blockIdx.x * 256;
  {
    int n = n0 + t;
    bs[t] = (n < NN) ? batch[n] : -1;
  }
  __syncthreads();
  int cur = bs[0];
  float acc = 0.f; int cnt = 0;
  for (int j = 0; j < 256; ++j){
    int nn = n0 + j;
    if (nn >= NN) break;
    int g = bs[j];
    if (g != cur){
      unsafeAtomicAdd(&gsum[cur*256 + t], acc);
      if (t == 0) unsafeAtomicAdd(&gcnt[cur], (float)cnt);
      acc = 0.f; cnt = 0; cur = g;
    }
    acc += bf2f(EH[(long long)nn*256 + t]) + bf2f(EL[(long long)nn*256 + t]);
    ++cnt;
  }
  if (cnt > 0 && cur >= 0){
    unsafeAtomicAdd(&gsum[cur*256 + t], acc);
    if (t == 0) unsafeAtomicAdd(&gcnt[cur], (float)cnt);
  }
}

// ---------------- scorer MLP (pool-finalize + concat fused in) ----------------
__global__ void k_score(const float* __restrict__ gsum, const float* __restrict__ gcnt,
                        const float* __restrict__ hfin, const float* __restrict__ wm1,
                        const float* __restrict__ bm1, const float* __restrict__ wm2,
                        const float* __restrict__ bm2, float* __restrict__ out)
{
  __shared__ float cs[512];
  __shared__ float red[4];
  const int b = blockIdx.x, t = threadIdx.x;
  float inv = 1.0f / fmaxf(gcnt[b], 1.0f);
  cs[t]       = gsum[b*256 + t] * inv;
  cs[256 + t] = hfin[b*256 + t];
  __syncthreads();
  float v = 0.f;
  #pragma unroll 4
  for (int k = 0; k < 512; ++k) v = fmaf(cs[k], wm1[(long long)k*256 + t], v);
  v = fmaxf(v + bm1[t], 0.f) * wm2[t];
  #pragma unroll
  for (int off = 32; off > 0; off >>= 1) v += __shfl_down(v, off, 64);
  if ((t & 63) == 0) red[t >> 6] = v;
  __syncthreads();
  if (t == 0) out[b] = red[0] + red[1] + red[2] + red[3] + bm2[0];
}

} // namespace

extern "C" void kernel_launch(void* const* d_in, const int* in_sizes, int n_in,
                              void* d_out, int out_size, void* d_ws, size_t ws_size,
                              hipStream_t stream)
{
  const float* x     = (const float*)d_in[0];
  const int*   eidx  = (const int*)  d_in[1];
  const int*   batch = (const int*)  d_in[2];
  const int*   paths = (const int*)  d_in[3];
  const float* w1l   = (const float*)d_in[4];
  const float* b1l   = (const float*)d_in[5];
  const float* w1r   = (const float*)d_in[6];
  const float* w2l   = (const float*)d_in[7];
  const float* b2l   = (const float*)d_in[8];
  const float* w2r   = (const float*)d_in[9];
  const float* w_ih  = (const float*)d_in[10];
  const float* w_hh  = (const float*)d_in[11];
  const float* b_ih  = (const float*)d_in[12];
  const float* b_hh  = (const float*)d_in[13];
  const float* wm1   = (const float*)d_in[14];
  const float* bm1   = (const float*)d_in[15];
  const float* wm2   = (const float*)d_in[16];
  const float* bm2   = (const float*)d_in[17];

  const int* src = eidx;        // edge_index[0]
  const int* dst = eidx + NE;   // edge_index[1]

  // workspace layout (same footprint as before, ~138 MB)
  float* w    = (float*)d_ws;
  float* bufA = w;                         // region0: gather out hi/lo (2 x NN*ND ushort)
  float* bufB = bufA + (long long)NN*ND;   // region1: h1 hi/lo -> node_emb hi/lo in-place
  float* xg   = bufB + (long long)NN*ND;   // 2048*1024 floats
  float* gsum = xg   + 2048*1024;          // 64*256
  float* gcnt = gsum + NB*ND;              // 64
  float* h0   = gcnt + 64;                 // 64*256
  float* c0   = h0   + NB*ND;              // 64*256
  float* h1   = c0   + NB*ND;              // 64*256
  ushort* wt1H = (ushort*)(h1 + NB*ND);    // 256*512 each (bf16, fragment-swizzled)
  ushort* wt1L = wt1H + 256*512;
  ushort* wt2H = wt1L + 256*512;
  ushort* wt2L = wt2H + 256*512;
  ushort* fb16 = wt2L + 256*512;           // N*256 bf16 (x copy, then h1 copy — never both live)

  ushort* A1H = (ushort*)bufA;             // gather mean, hi
  ushort* A1L = A1H + (long long)NN*ND;    // gather mean, lo
  ushort* h1H = (ushort*)bufB;             // h1 hi (layer1 out) -> node_emb hi (layer2 out, in-place)
  ushort* h1L = h1H + (long long)NN*ND;

  // CSR scratch aliased into xg region (dead until k_xgate runs, after layer 2)
  int* cnt    = (int*)xg;        // 50432
  int* offs   = cnt    + 50432;  // 50432
  int* cursor = offs   + 50432;  // 50432
  int* bsum   = cursor + 50432;  // 256
  int* bsum2  = bsum   + 256;    // 256
  int* csr    = bsum2  + 256;    // 800000

  // ---- weight prep (fragment-swizzled bf16 hi/lo split) ----
  k_wsplit<<<512, 256, 0, stream>>>(w1l, w1r, wt1H, wt1L);
  k_wsplit<<<512, 256, 0, stream>>>(w2l, w2r, wt2H, wt2L);

  // ---- x -> bf16 copy for the mean-agg path ----
  k_tobf16<<<(NN*ND/8 + 255)/256, 256, 0, stream>>>(x, fb16);

  // ---- build CSR (counting sort by dst), shared by both layers ----
  hipMemsetAsync(cnt, 0, 50432*sizeof(int), stream);
  k_hist<<<1024, 256, 0, stream>>>(dst, cnt);
  k_scan_block<<<NSCAN, 256, 0, stream>>>(cnt, offs, bsum);
  k_scan_top<<<1, 256, 0, stream>>>(bsum, bsum2);
  k_scan_add<<<NSCAN, 256, 0, stream>>>(offs, bsum2, cursor);
  k_fill<<<1024, 256, 0, stream>>>(src, dst, cursor, csr);

  // ---- layer 1: bf16 gather-mean (pre-split), MFMA GEMM (A2 = x fp32 staged+split) ----
  k_gather_bf16<<<NN, 256, 0, stream>>>(fb16, offs, csr, A1H, A1L);
  k_gemm_mfma<<<(NN+63)/64, 256, 0, stream>>>(A1H, A1L, nullptr, nullptr, x,
                                              wt1H, wt1L, b1l, h1H, h1L, fb16, 1, 1);

  // ---- layer 2: gather over relu(h1) bf16; GEMM writes node_emb hi/lo in-place over h1 ----
  k_gather_bf16<<<NN, 256, 0, stream>>>(fb16, offs, csr, A1H, A1L);
  k_gemm_mfma<<<(NN+63)/64, 256, 0, stream>>>(A1H, A1L, h1H, h1L, nullptr,
                                              wt2H, wt2L, b2l, h1H, h1L, (ushort*)nullptr, 0, 0);

  // ---- global mean pool ----
  hipMemsetAsync(gsum, 0, (NB*ND + 64)*sizeof(float), stream);
  k_pool<<<(NN+255)/256, 256, 0, stream>>>(h1H, h1L, batch, gsum, gcnt);

  // ---- LSTM input gates (overwrites the CSR alias region — CSR dead by now) ----
  k_xgate<<<dim3((NB*NL)/64, 1024/256), 256, 0, stream>>>(h1H, h1L, paths, w_ih, b_ih, b_hh, xg);

  // ---- LSTM recurrence: 32 launches, ping-pong h buffers ----
  hipMemsetAsync(h0, 0, 2*(size_t)NB*ND*sizeof(float), stream);  // h0 + c0
  for (int ts = 0; ts < NL; ++ts){
    float* hin  = (ts & 1) ? h1 : h0;
    float* hout = (ts & 1) ? h0 : h1;
    k_lstm_step<<<512, 256, 0, stream>>>(hin, hout, c0, xg, w_hh, ts);
  }
  // ts=31 wrote h0 -> final hidden state

  // ---- fused concat + scorer ----
  k_score<<<NB, 256, 0, stream>>>(gsum, gcnt, h0, wm1, bm1, wm2, bm2, (float*)d_out);
}

// Round 2
// 785.982 us; speedup vs baseline: 1.0844x; 1.0805x over previous
//
#include <hip/hip_runtime.h>

namespace {

constexpr int NN = 50000;   // nodes
constexpr int NE = 800000;  // edges
constexpr int NB = 64;      // graphs / batch
constexpr int NL = 32;      // path length
constexpr int ND = 256;     // D == H == 256
constexpr int NSCAN = 196;  // ceil(50176/256) scan blocks
constexpr int NPOOL = (NN + 63) / 64;  // 782 pool blocks

typedef __attribute__((ext_vector_type(8))) short short8v;  // 8 bf16 (4 VGPRs)
typedef __attribute__((ext_vector_type(4))) float float4v;  // MFMA accumulator

// async global->LDS, 16B per lane, linear dest (wave-uniform base + lane*16)
#define GLD16(GP, LP) __builtin_amdgcn_global_load_lds( \
    (const __attribute__((address_space(1))) void*)(GP), \
    (__attribute__((address_space(3))) void*)(LP), 16, 0, 0)

__device__ __forceinline__ float sigf(float x){ return 1.0f/(1.0f + __expf(-x)); }

__device__ __forceinline__ ushort rne_bf16(float f){
  uint u = __float_as_uint(f);
  return (ushort)((u + 0x7FFFu + ((u >> 16) & 1u)) >> 16);
}
__device__ __forceinline__ float bf2f(ushort u){ return __uint_as_float((uint)u << 16); }

// hi = trunc-bf16(f) (exact bits), lo = trunc-bf16(f - hi) — identical math to split8
__device__ __forceinline__ void split1(float f, ushort& h, ushort& lo){
  uint u = __float_as_uint(f);
  h = (ushort)(u >> 16);
  float r = f - __uint_as_float(u & 0xFFFF0000u);
  lo = (ushort)(__float_as_uint(r) >> 16);
}

// split 8 fp32 -> 8 bf16-hi (truncated; exact bits) + 8 bf16-lo (of remainder)
__device__ __forceinline__ void split8(float4 fa, float4 fb, uint4& h, uint4& lo){
  uint a0=__float_as_uint(fa.x), a1=__float_as_uint(fa.y), a2=__float_as_uint(fa.z), a3=__float_as_uint(fa.w);
  uint b0=__float_as_uint(fb.x), b1=__float_as_uint(fb.y), b2=__float_as_uint(fb.z), b3=__float_as_uint(fb.w);
  h.x = (a0>>16) | (a1 & 0xFFFF0000u);
  h.y = (a2>>16) | (a3 & 0xFFFF0000u);
  h.z = (b0>>16) | (b1 & 0xFFFF0000u);
  h.w = (b2>>16) | (b3 & 0xFFFF0000u);
  float r0 = fa.x - __uint_as_float(a0 & 0xFFFF0000u);
  float r1 = fa.y - __uint_as_float(a1 & 0xFFFF0000u);
  float r2 = fa.z - __uint_as_float(a2 & 0xFFFF0000u);
  float r3 = fa.w - __uint_as_float(a3 & 0xFFFF0000u);
  float r4 = fb.x - __uint_as_float(b0 & 0xFFFF0000u);
  float r5 = fb.y - __uint_as_float(b1 & 0xFFFF0000u);
  float r6 = fb.z - __uint_as_float(b2 & 0xFFFF0000u);
  float r7 = fb.w - __uint_as_float(b3 & 0xFFFF0000u);
  lo.x = (__float_as_uint(r0)>>16) | (__float_as_uint(r1) & 0xFFFF0000u);
  lo.y = (__float_as_uint(r2)>>16) | (__float_as_uint(r3) & 0xFFFF0000u);
  lo.z = (__float_as_uint(r4)>>16) | (__float_as_uint(r5) & 0xFFFF0000u);
  lo.w = (__float_as_uint(r6)>>16) | (__float_as_uint(r7) & 0xFFFF0000u);
}

// ================= CSR build (counting sort of edges by dst) =================
__global__ void k_hist(const int* __restrict__ dst, int* __restrict__ cnt){
  int stride = gridDim.x * blockDim.x;
  for (int e = blockIdx.x*blockDim.x + threadIdx.x; e < NE; e += stride)
    atomicAdd(&cnt[dst[e]], 1);
}

__global__ void k_scan_block(const int* __restrict__ cnt, int* __restrict__ offs,
                             int* __restrict__ bsum){
  __shared__ int s[256];
  const int t = threadIdx.x, i = blockIdx.x*256 + t;
  int v = cnt[i];
  s[t] = v; __syncthreads();
  #pragma unroll
  for (int off = 1; off < 256; off <<= 1){
    int x = (t >= off) ? s[t-off] : 0;
    __syncthreads();
    s[t] += x;
    __syncthreads();
  }
  offs[i] = s[t] - v;
  if (t == 255) bsum[blockIdx.x] = s[255];
}

__global__ void k_scan_top(const int* __restrict__ bsum, int* __restrict__ bsum2){
  __shared__ int s[256];
  const int t = threadIdx.x;
  int v = (t < NSCAN) ? bsum[t] : 0;
  s[t] = v; __syncthreads();
  #pragma unroll
  for (int off = 1; off < 256; off <<= 1){
    int x = (t >= off) ? s[t-off] : 0;
    __syncthreads();
    s[t] += x;
    __syncthreads();
  }
  if (t < NSCAN) bsum2[t] = s[t] - v;
}

__global__ void k_scan_add(int* __restrict__ offs, const int* __restrict__ bsum2,
                           int* __restrict__ cursor){
  const int i = blockIdx.x*256 + threadIdx.x;
  int v = offs[i] + bsum2[blockIdx.x];
  offs[i] = v;
  cursor[i] = v;
}

__global__ void k_fill(const int* __restrict__ src, const int* __restrict__ dst,
                       int* __restrict__ cursor, int* __restrict__ csr){
  int stride = gridDim.x * blockDim.x;
  for (int e = blockIdx.x*blockDim.x + threadIdx.x; e < NE; e += stride){
    int d = dst[e];
    int pos = atomicAdd(&cursor[d], 1);
    csr[pos] = src[e];
  }
}

// ================= fp32 -> bf16 (RNE) bulk convert =================
__global__ void k_tobf16(const float* __restrict__ in, ushort* __restrict__ out){
  const int i = blockIdx.x*blockDim.x + threadIdx.x;   // one per 8 elems
  const float4 a = ((const float4*)in)[i*2];
  const float4 b = ((const float4*)in)[i*2+1];
  ushort o[8] = { rne_bf16(a.x), rne_bf16(a.y), rne_bf16(a.z), rne_bf16(a.w),
                  rne_bf16(b.x), rne_bf16(b.y), rne_bf16(b.z), rne_bf16(b.w) };
  ((uint4*)out)[i] = *(uint4*)o;
}

// ================= mean-aggregate gather over bf16 features =================
__launch_bounds__(256, 8)
__global__ void k_gather_bf16(const ushort* __restrict__ feat, const int* __restrict__ offs,
                              const int* __restrict__ csr,
                              ushort* __restrict__ outH, ushort* __restrict__ outL){
  __shared__ float4 sp[256];
  const int u = blockIdx.x, t = threadIdx.x;
  const int w = t >> 6, l = t & 63;
  const int beg = offs[u], end = offs[u+1];
  const int lc = l * 4;
  float a0 = 0.f, a1 = 0.f, a2 = 0.f, a3 = 0.f;
  int e = beg + w;
  for (; e + 4 < end; e += 8){
    int s0 = csr[e], s1 = csr[e+4];
    ushort4 v0 = *(const ushort4*)(feat + (long long)s0*ND + lc);
    ushort4 v1 = *(const ushort4*)(feat + (long long)s1*ND + lc);
    a0 += bf2f(v0.x) + bf2f(v1.x);
    a1 += bf2f(v0.y) + bf2f(v1.y);
    a2 += bf2f(v0.z) + bf2f(v1.z);
    a3 += bf2f(v0.w) + bf2f(v1.w);
  }
  if (e < end){
    int s0 = csr[e];
    ushort4 v0 = *(const ushort4*)(feat + (long long)s0*ND + lc);
    a0 += bf2f(v0.x); a1 += bf2f(v0.y); a2 += bf2f(v0.z); a3 += bf2f(v0.w);
  }
  sp[t] = make_float4(a0, a1, a2, a3);
  __syncthreads();
  if (t < 64){
    float4 p0 = sp[t], p1 = sp[64+t], p2 = sp[128+t], p3 = sp[192+t];
    float inv = 1.0f / fmaxf((float)(end - beg), 1.0f);
    float4 r;
    r.x = (p0.x + p1.x + p2.x + p3.x) * inv;
    r.y = (p0.y + p1.y + p2.y + p3.y) * inv;
    r.z = (p0.z + p1.z + p2.z + p3.z) * inv;
    r.w = (p0.w + p1.w + p2.w + p3.w) * inv;
    ushort hh[4], ll[4];
    split1(r.x, hh[0], ll[0]);
    split1(r.y, hh[1], ll[1]);
    split1(r.z, hh[2], ll[2]);
    split1(r.w, hh[3], ll[3]);
    *(ushort4*)(outH + (long long)u*ND + t*4) = *(ushort4*)hh;
    *(ushort4*)(outL + (long long)u*ND + t*4) = *(ushort4*)ll;
  }
}

// ============ weight prep: fragment-linear swizzled [wl; wr] bf16 hi/lo ============
__global__ void k_wsplit(const float* __restrict__ wl, const float* __restrict__ wr,
                         ushort* __restrict__ WtH, ushort* __restrict__ WtL){
  const int k = blockIdx.x;    // 0..511
  const int n = threadIdx.x;   // 0..255
  float v = (k < 256) ? wl[k*256 + n] : wr[(k-256)*256 + n];
  uint u = __float_as_uint(v);
  float r = v - __uint_as_float(u & 0xFFFF0000u);
  const int wc = n >> 6, nt = (n >> 4) & 3, lm = n & 15;
  const int kk = k >> 5, lq = (k >> 3) & 3, j = k & 7;
  const long long idx = (long long)(((wc*4 + nt)*16 + kk)*64 + lq*16 + lm)*8 + j;
  WtH[idx] = (ushort)(u >> 16);
  WtL[idx] = (ushort)(__float_as_uint(r) >> 16);
}

// ============ MFMA SAGE GEMM: LDS-staged A (global_load_lds dbuf), pre-split hi/lo ============
__launch_bounds__(256, 3)
__global__ void k_gemm_mfma(const ushort* __restrict__ A1H, const ushort* __restrict__ A1L,
                            const ushort* __restrict__ A2H, const ushort* __restrict__ A2L,
                            const float* __restrict__ A2F,
                            const ushort* __restrict__ WtH, const ushort* __restrict__ WtL,
                            const float* __restrict__ bias,
                            ushort* __restrict__ CH, ushort* __restrict__ CL,
                            ushort* __restrict__ Cb, int relu, int a2f32)
{
  __shared__ float eb[16*260];          // 16.64 KB; first 16 KB doubles as staging dbuf
  char* const sm = (char*)eb;

  const int t  = threadIdx.x;
  const int w  = t >> 6;                // wave 0..3
  const int l  = t & 63;                // lane
  const int lm = l & 15;
  const int lq = l >> 4;
  const int m0 = blockIdx.x * 64;

  const uint4* BH4 = (const uint4*)WtH;
  const uint4* BL4 = (const uint4*)WtL;

  const float4v vzero = {0.f, 0.f, 0.f, 0.f};
  float4v acc[4][4];
  #pragma unroll
  for (int i = 0; i < 4; ++i)
    #pragma unroll
    for (int j = 0; j < 4; ++j) acc[i][j] = vzero;

  int bbase[4];
  #pragma unroll
  for (int nt = 0; nt < 4; ++nt) bbase[nt] = (w*4 + nt)*1024 + l;

  const int j0 = w * 2;   // this wave's pair of staging instructions (of 8 per K-step)

  auto stageHL = [&](int bb, const ushort* __restrict__ H, const ushort* __restrict__ L, int k0){
    #pragma unroll
    for (int jj = 0; jj < 2; ++jj){
      const int j   = j0 + jj;        // 0..7
      const int arr = j >> 2;         // 0 = hi, 1 = lo
      const int i   = j & 3;          // 1KB instr within array
      const int row = i*16 + (l >> 2);
      int rg = m0 + row; rg = (rg < NN) ? rg : (NN - 1);
      const int g = (l & 3) ^ ((row >> 1) & 3);
      const ushort* srcp = (arr ? L : H) + (long long)rg*ND + k0 + g*8;
      GLD16(srcp, sm + bb + arr*4096 + i*1024);
    }
  };
  auto stageF = [&](int bb, int k0){
    #pragma unroll
    for (int jj = 0; jj < 2; ++jj){
      const int j   = j0 + jj;        // 0..7
      const int row = j*8 + (l >> 3);
      int rg = m0 + row; rg = (rg < NN) ? rg : (NN - 1);
      const int g = (l & 7) ^ (row & 7);
      const float* srcp = A2F + (long long)rg*ND + k0 + g*4;
      GLD16(srcp, sm + bb + j*1024);
    }
  };
  auto stage = [&](int bb, int kk){
    if (kk < 8)      stageHL(bb, A1H, A1L, kk*32);
    else if (!a2f32) stageHL(bb, A2H, A2L, (kk - 8)*32);
    else             stageF (bb, (kk - 8)*32);
  };

  stage(0, 0);
  __syncthreads();   // drains vmcnt: buf0 ready

  #pragma unroll
  for (int kk = 0; kk < 16; ++kk){
    const int bb = (kk & 1) * 8192;

    uint4 bh[4], bl[4];
    #pragma unroll
    for (int nt = 0; nt < 4; ++nt){
      const int idx = bbase[nt] + kk*64;
      bh[nt] = BH4[idx];
      bl[nt] = BL4[idx];
    }

    if (kk < 15) stage(bb ^ 8192, kk + 1);

    uint4 ah[4], al[4];
    if (kk < 8 || !a2f32){
      #pragma unroll
      for (int mt = 0; mt < 4; ++mt){
        const int row = mt*16 + lm;
        const int off = bb + row*64 + ((lq ^ ((row >> 1) & 3)) << 4);
        ah[mt] = *(const uint4*)(sm + off);
        al[mt] = *(const uint4*)(sm + 4096 + off);
      }
    } else {
      #pragma unroll
      for (int mt = 0; mt < 4; ++mt){
        const int row = mt*16 + lm;
        const int s = row & 7;
        const float4 fa = *(const float4*)(sm + bb + row*128 + (((2*lq    ) ^ s) << 4));
        const float4 fb = *(const float4*)(sm + bb + row*128 + (((2*lq + 1) ^ s) << 4));
        split8(fa, fb, ah[mt], al[mt]);
      }
    }

    #pragma unroll
    for (int nt = 0; nt < 4; ++nt){
      short8v bhv = *(short8v*)&bh[nt];
      short8v blv = *(short8v*)&bl[nt];
      #pragma unroll
      for (int mt = 0; mt < 4; ++mt){
        short8v ahv = *(short8v*)&ah[mt];
        short8v alv = *(short8v*)&al[mt];
        acc[mt][nt] = __builtin_amdgcn_mfma_f32_16x16x32_bf16(ahv, bhv, acc[mt][nt], 0, 0, 0);
        acc[mt][nt] = __builtin_amdgcn_mfma_f32_16x16x32_bf16(alv, bhv, acc[mt][nt], 0, 0, 0);
        acc[mt][nt] = __builtin_amdgcn_mfma_f32_16x16x32_bf16(ahv, blv, acc[mt][nt], 0, 0, 0);
      }
    }
    __syncthreads();
  }

  // ---- epilogue: LDS transpose per 16-row slab, coalesced hi/lo bf16 stores ----
  float bvv[4];
  #pragma unroll
  for (int nt = 0; nt < 4; ++nt) bvv[nt] = bias[w*64 + nt*16 + lm];

  #pragma unroll
  for (int mt = 0; mt < 4; ++mt){
    #pragma unroll
    for (int nt = 0; nt < 4; ++nt){
      #pragma unroll
      for (int r = 0; r < 4; ++r){
        float v = acc[mt][nt][r] + bvv[nt];
        if (relu) v = fmaxf(v, 0.f);
        eb[(lq*4 + r)*260 + w*64 + nt*16 + lm] = v;   // C/D: col=lane&15, row=quad*4+reg
      }
    }
    __syncthreads();
    #pragma unroll
    for (int i = 0; i < 4; ++i){
      int idx = i*256 + t;           // 0..1023
      int rr  = idx >> 6;            // 0..15
      int c4  = (idx & 63) * 4;      // 0..252
      int grow = m0 + mt*16 + rr;
      if (grow < NN){
        float4 fv = *(float4*)&eb[rr*260 + c4];
        ushort hh[4], ll[4];
        split1(fv.x, hh[0], ll[0]);
        split1(fv.y, hh[1], ll[1]);
        split1(fv.z, hh[2], ll[2]);
        split1(fv.w, hh[3], ll[3]);
        *(ushort4*)(CH + (long long)grow*ND + c4) = *(ushort4*)hh;
        *(ushort4*)(CL + (long long)grow*ND + c4) = *(ushort4*)ll;
        if (Cb){
          ushort ub[4] = { rne_bf16(fv.x), rne_bf16(fv.y), rne_bf16(fv.z), rne_bf16(fv.w) };
          *(ushort4*)(Cb + (long long)grow*ND + c4) = *(ushort4*)ub;
        }
      }
    }
    __syncthreads();
  }
}

// ---------------- LSTM input gates ----------------
__launch_bounds__(256, 3)
__global__ void k_xgate(const ushort* __restrict__ EH, const ushort* __restrict__ EL,
                        const int* __restrict__ paths,
                        const float* __restrict__ w_ih, const float* __restrict__ b_ih,
                        const float* __restrict__ b_hh, float* __restrict__ xg)
{
  __shared__ float As[16][68];
  __shared__ float Ws[16][260];
  const int t  = threadIdx.x;
  const int m0 = blockIdx.x * 64;    // path rows (2048 total)
  const int g0 = blockIdx.y * 256;   // gate cols (1024 total)
  const int rg = t >> 5, cg = t & 31;
  const int sm = t >> 2, sj = (t & 3) * 4;

  float acc[8][8];
  #pragma unroll
  for (int i = 0; i < 8; ++i)
    #pragma unroll
    for (int j = 0; j < 8; ++j) acc[i][j] = 0.f;

  const int node = paths[m0 + sm];
  const ushort* ehrow = EH + (long long)node*ND;
  const ushort* elrow = EL + (long long)node*ND;
  const float* wrow = w_ih + (long long)(g0 + t)*ND;

  for (int k0 = 0; k0 < 256; k0 += 16){
    ushort4 hv = *(const ushort4*)(ehrow + k0 + sj);
    ushort4 lv = *(const ushort4*)(elrow + k0 + sj);
    float av0 = bf2f(hv.x) + bf2f(lv.x);
    float av1 = bf2f(hv.y) + bf2f(lv.y);
    float av2 = bf2f(hv.z) + bf2f(lv.z);
    float av3 = bf2f(hv.w) + bf2f(lv.w);
    float4 q0 = *(const float4*)(wrow + k0 + 0);
    float4 q1 = *(const float4*)(wrow + k0 + 4);
    float4 q2 = *(const float4*)(wrow + k0 + 8);
    float4 q3 = *(const float4*)(wrow + k0 + 12);
    __syncthreads();
    As[sj+0][sm]=av0; As[sj+1][sm]=av1; As[sj+2][sm]=av2; As[sj+3][sm]=av3;
    Ws[ 0][t]=q0.x; Ws[ 1][t]=q0.y; Ws[ 2][t]=q0.z; Ws[ 3][t]=q0.w;
    Ws[ 4][t]=q1.x; Ws[ 5][t]=q1.y; Ws[ 6][t]=q1.z; Ws[ 7][t]=q1.w;
    Ws[ 8][t]=q2.x; Ws[ 9][t]=q2.y; Ws[10][t]=q2.z; Ws[11][t]=q2.w;
    Ws[12][t]=q3.x; Ws[13][t]=q3.y; Ws[14][t]=q3.z; Ws[15][t]=q3.w;
    __syncthreads();
    #pragma unroll
    for (int k = 0; k < 16; ++k){
      float a[8], b[8];
      *(float4*)&a[0] = *(const float4*)&As[k][rg*8];
      *(float4*)&a[4] = *(const float4*)&As[k][rg*8+4];
      *(float4*)&b[0] = *(const float4*)&Ws[k][cg*8];
      *(float4*)&b[4] = *(const float4*)&Ws[k][cg*8+4];
      #pragma unroll
      for (int i = 0; i < 8; ++i)
        #pragma unroll
        for (int j = 0; j < 8; ++j)
          acc[i][j] = fmaf(a[i], b[j], acc[i][j]);
    }
  }

  float bv[8];
  #pragma unroll
  for (int j = 0; j < 8; ++j){ int g = g0 + cg*8 + j; bv[j] = b_ih[g] + b_hh[g]; }
  #pragma unroll
  for (int i = 0; i < 8; ++i){
    int row = m0 + rg*8 + i;
    float o[8];
    #pragma unroll
    for (int j = 0; j < 8; ++j) o[j] = acc[i][j] + bv[j];
    *(float4*)(xg + (long long)row*1024 + g0 + cg*8 + 0) = *(float4*)&o[0];
    *(float4*)(xg + (long long)row*1024 + g0 + cg*8 + 4) = *(float4*)&o[4];
  }
}

// ---------------- one LSTM step ----------------
__launch_bounds__(256, 4)
__global__ void k_lstm_step(const float* __restrict__ h_in, float* __restrict__ h_out,
                            float* __restrict__ c_state, const float* __restrict__ xg,
                            const float* __restrict__ w_hh, int tstep)
{
  __shared__ float ws[4*256];
  __shared__ float hs[32*260];
  __shared__ float part[2*128];
  __shared__ float gs[128];
  const int t  = threadIdx.x;
  const int u  = blockIdx.x >> 1;
  const int b0 = (blockIdx.x & 1) * 32;

  {
    int gate = t >> 6, c4 = (t & 63) * 4;
    float4 v = *(const float4*)(w_hh + (long long)(gate*256 + u)*256 + c4);
    *(float4*)&ws[gate*256 + c4] = v;
  }
  #pragma unroll
  for (int i = 0; i < 8; ++i){
    int idx = i*256 + t;
    int b = idx >> 6, c4 = (idx & 63) * 4;
    float4 v = *(const float4*)(h_in + (long long)(b0 + b)*256 + c4);
    *(float4*)&hs[b*260 + c4] = v;
  }
  __syncthreads();

  const int b  = t & 31;
  const int g  = (t >> 5) & 3;
  const int kd = t >> 7;
  float s = 0.f;
  const float* hp = &hs[b*260 + kd*128];
  const float* wp = &ws[g*256 + kd*128];
  #pragma unroll
  for (int k4 = 0; k4 < 32; ++k4){
    float4 h4 = *(const float4*)(hp + k4*4);
    float4 w4 = *(const float4*)(wp + k4*4);
    s += h4.x*w4.x + h4.y*w4.y + h4.z*w4.z + h4.w*w4.w;
  }
  part[kd*128 + b*4 + g] = s;
  __syncthreads();

  if (t < 128){
    int bb = t >> 2, gg = t & 3;
    const float* xp = xg + ((long long)(b0 + bb)*NL + tstep)*1024;
    gs[t] = part[t] + part[128 + t] + xp[gg*256 + u];
  }
  __syncthreads();

  if (t < 32){
    float gi = gs[t*4+0], gf = gs[t*4+1], gG = gs[t*4+2], go = gs[t*4+3];
    int bb = b0 + t;
    float c_old = c_state[bb*256 + u];
    float c_new = sigf(gf)*c_old + sigf(gi)*tanhf(gG);
    c_state[bb*256 + u] = c_new;
    h_out[bb*256 + u] = sigf(go)*tanhf(c_new);
  }
}

// ---------------- global mean pool (hi/lo bf16 input), chunk-parallel ----------------
// 782 blocks x 64 rows. Thread (r=t>>5, c=t&31) owns rows r*8..r*8+7 x cols c*8..c*8+7,
// loading uint4 hi + uint4 lo per row (coalesced 16B). Common case (chunk entirely one
// graph): LDS cross-r reduce -> 1 atomic per column. Rare boundary chunks: per-thread
// segment flush. fp32 accumulate + unsafeAtomicAdd, same math as before.
__launch_bounds__(256, 8)
__global__ void k_pool(const ushort* __restrict__ EH, const ushort* __restrict__ EL,
                       const int* __restrict__ batch,
                       float* __restrict__ gsum, float* __restrict__ gcnt)
{
  __shared__ int bs[64];
  __shared__ int uni;
  __shared__ float spf[8*256];
  const int t  = threadIdx.x;
  const int m0 = blockIdx.x * 64;
  const int r  = t >> 5;        // row-lane 0..7
  const int c  = t & 31;        // colgroup 0..31 (8 elems each)
  if (t == 0) uni = 1;
  if (t < 64){
    int n = m0 + t;
    bs[t] = (n < NN) ? batch[n] : -1;
  }
  __syncthreads();
  if (t < 64 && bs[t] != bs[0]) uni = 0;
  __syncthreads();

  const ushort* eh = EH + (long long)m0*ND + c*8;
  const ushort* el = EL + (long long)m0*ND + c*8;

  if (uni){
    float a[8];
    #pragma unroll
    for (int j = 0; j < 8; ++j) a[j] = 0.f;
    #pragma unroll
    for (int i = 0; i < 8; ++i){
      const int row = r*8 + i;
      const uint4 hv = *(const uint4*)(eh + (long long)row*ND);
      const uint4 lv = *(const uint4*)(el + (long long)row*ND);
      const ushort* hp = (const ushort*)&hv;
      const ushort* lp = (const ushort*)&lv;
      #pragma unroll
      for (int j = 0; j < 8; ++j) a[j] += bf2f(hp[j]) + bf2f(lp[j]);
    }
    #pragma unroll
    for (int j = 0; j < 8; ++j) spf[r*256 + c*8 + j] = a[j];
    __syncthreads();
    float s = spf[t] + spf[256+t] + spf[512+t] + spf[768+t]
            + spf[1024+t] + spf[1280+t] + spf[1536+t] + spf[1792+t];
    const int g = bs[0];
    unsafeAtomicAdd(&gsum[g*256 + t], s);
    if (t == 0) unsafeAtomicAdd(&gcnt[g], 64.0f);
  } else {
    float a[8];
    #pragma unroll
    for (int j = 0; j < 8; ++j) a[j] = 0.f;
    int cur = -1, cnt = 0;
    #pragma unroll
    for (int i = 0; i < 8; ++i){
      const int row = r*8 + i;
      const int g = bs[row];
      if (g != cur){
        if (cur >= 0){
          #pragma unroll
          for (int j = 0; j < 8; ++j) unsafeAtomicAdd(&gsum[cur*256 + c*8 + j], a[j]);
          if (c == 0) unsafeAtomicAdd(&gcnt[cur], (float)cnt);
        }
        #pragma unroll
        for (int j = 0; j < 8; ++j) a[j] = 0.f;
        cnt = 0; cur = g;
      }
      if (g >= 0){
        const uint4 hv = *(const uint4*)(eh + (long long)row*ND);
        const uint4 lv = *(const uint4*)(el + (long long)row*ND);
        const ushort* hp = (const ushort*)&hv;
        const ushort* lp = (const ushort*)&lv;
        #pragma unroll
        for (int j = 0; j < 8; ++j) a[j] += bf2f(hp[j]) + bf2f(lp[j]);
        ++cnt;
      }
    }
    if (cur >= 0){
      #pragma unroll
      for (int j = 0; j < 8; ++j) unsafeAtomicAdd(&gsum[cur*256 + c*8 + j], a[j]);
      if (c == 0) unsafeAtomicAdd(&gcnt[cur], (float)cnt);
    }
  }
}

// ---------------- scorer MLP (pool-finalize + concat fused in) ----------------
__global__ void k_score(const float* __restrict__ gsum, const float* __restrict__ gcnt,
                        const float* __restrict__ hfin, const float* __restrict__ wm1,
                        const float* __restrict__ bm1, const float* __restrict__ wm2,
                        const float* __restrict__ bm2, float* __restrict__ out)
{
  __shared__ float cs[512];
  __shared__ float red[4];
  const int b = blockIdx.x, t = threadIdx.x;
  float inv = 1.0f / fmaxf(gcnt[b], 1.0f);
  cs[t]       = gsum[b*256 + t] * inv;
  cs[256 + t] = hfin[b*256 + t];
  __syncthreads();
  float v = 0.f;
  #pragma unroll 4
  for (int k = 0; k < 512; ++k) v = fmaf(cs[k], wm1[(long long)k*256 + t], v);
  v = fmaxf(v + bm1[t], 0.f) * wm2[t];
  #pragma unroll
  for (int off = 32; off > 0; off >>= 1) v += __shfl_down(v, off, 64);
  if ((t & 63) == 0) red[t >> 6] = v;
  __syncthreads();
  if (t == 0) out[b] = red[0] + red[1] + red[2] + red[3] + bm2[0];
}

} // namespace

extern "C" void kernel_launch(void* const* d_in, const int* in_sizes, int n_in,
                              void* d_out, int out_size, void* d_ws, size_t ws_size,
                              hipStream_t stream)
{
  const float* x     = (const float*)d_in[0];
  const int*   eidx  = (const int*)  d_in[1];
  const int*   batch = (const int*)  d_in[2];
  const int*   paths = (const int*)  d_in[3];
  const float* w1l   = (const float*)d_in[4];
  const float* b1l   = (const float*)d_in[5];
  const float* w1r   = (const float*)d_in[6];
  const float* w2l   = (const float*)d_in[7];
  const float* b2l   = (const float*)d_in[8];
  const float* w2r   = (const float*)d_in[9];
  const float* w_ih  = (const float*)d_in[10];
  const float* w_hh  = (const float*)d_in[11];
  const float* b_ih  = (const float*)d_in[12];
  const float* b_hh  = (const float*)d_in[13];
  const float* wm1   = (const float*)d_in[14];
  const float* bm1   = (const float*)d_in[15];
  const float* wm2   = (const float*)d_in[16];
  const float* bm2   = (const float*)d_in[17];

  const int* src = eidx;        // edge_index[0]
  const int* dst = eidx + NE;   // edge_index[1]

  // workspace layout (same footprint as before, ~138 MB)
  float* w    = (float*)d_ws;
  float* bufA = w;                         // region0: gather out hi/lo (2 x NN*ND ushort)
  float* bufB = bufA + (long long)NN*ND;   // region1: h1 hi/lo -> node_emb hi/lo in-place
  float* xg   = bufB + (long long)NN*ND;   // 2048*1024 floats
  float* gsum = xg   + 2048*1024;          // 64*256
  float* gcnt = gsum + NB*ND;              // 64
  float* h0   = gcnt + 64;                 // 64*256
  float* c0   = h0   + NB*ND;              // 64*256
  float* h1   = c0   + NB*ND;              // 64*256
  ushort* wt1H = (ushort*)(h1 + NB*ND);    // 256*512 each (bf16, fragment-swizzled)
  ushort* wt1L = wt1H + 256*512;
  ushort* wt2H = wt1L + 256*512;
  ushort* wt2L = wt2H + 256*512;
  ushort* fb16 = wt2L + 256*512;           // N*256 bf16 (x copy, then h1 copy — never both live)

  ushort* A1H = (ushort*)bufA;             // gather mean, hi
  ushort* A1L = A1H + (long long)NN*ND;    // gather mean, lo
  ushort* h1H = (ushort*)bufB;             // h1 hi (layer1 out) -> node_emb hi (layer2 out, in-place)
  ushort* h1L = h1H + (long long)NN*ND;

  // CSR scratch aliased into xg region (dead until k_xgate runs, after layer 2)
  int* cnt    = (int*)xg;        // 50432
  int* offs   = cnt    + 50432;  // 50432
  int* cursor = offs   + 50432;  // 50432
  int* bsum   = cursor + 50432;  // 256
  int* bsum2  = bsum   + 256;    // 256
  int* csr    = bsum2  + 256;    // 800000

  // ---- weight prep (fragment-swizzled bf16 hi/lo split) ----
  k_wsplit<<<512, 256, 0, stream>>>(w1l, w1r, wt1H, wt1L);
  k_wsplit<<<512, 256, 0, stream>>>(w2l, w2r, wt2H, wt2L);

  // ---- x -> bf16 copy for the mean-agg path ----
  k_tobf16<<<(NN*ND/8 + 255)/256, 256, 0, stream>>>(x, fb16);

  // ---- build CSR (counting sort by dst), shared by both layers ----
  hipMemsetAsync(cnt, 0, 50432*sizeof(int), stream);
  k_hist<<<1024, 256, 0, stream>>>(dst, cnt);
  k_scan_block<<<NSCAN, 256, 0, stream>>>(cnt, offs, bsum);
  k_scan_top<<<1, 256, 0, stream>>>(bsum, bsum2);
  k_scan_add<<<NSCAN, 256, 0, stream>>>(offs, bsum2, cursor);
  k_fill<<<1024, 256, 0, stream>>>(src, dst, cursor, csr);

  // ---- layer 1: bf16 gather-mean (pre-split), MFMA GEMM (A2 = x fp32 staged+split) ----
  k_gather_bf16<<<NN, 256, 0, stream>>>(fb16, offs, csr, A1H, A1L);
  k_gemm_mfma<<<(NN+63)/64, 256, 0, stream>>>(A1H, A1L, nullptr, nullptr, x,
                                              wt1H, wt1L, b1l, h1H, h1L, fb16, 1, 1);

  // ---- layer 2: gather over relu(h1) bf16; GEMM writes node_emb hi/lo in-place over h1 ----
  k_gather_bf16<<<NN, 256, 0, stream>>>(fb16, offs, csr, A1H, A1L);
  k_gemm_mfma<<<(NN+63)/64, 256, 0, stream>>>(A1H, A1L, h1H, h1L, nullptr,
                                              wt2H, wt2L, b2l, h1H, h1L, (ushort*)nullptr, 0, 0);

  // ---- global mean pool (chunk-parallel, vectorized) ----
  hipMemsetAsync(gsum, 0, (NB*ND + 64)*sizeof(float), stream);
  k_pool<<<NPOOL, 256, 0, stream>>>(h1H, h1L, batch, gsum, gcnt);

  // ---- LSTM input gates (overwrites the CSR alias region — CSR dead by now) ----
  k_xgate<<<dim3((NB*NL)/64, 1024/256), 256, 0, stream>>>(h1H, h1L, paths, w_ih, b_ih, b_hh, xg);

  // ---- LSTM recurrence: 32 launches, ping-pong h buffers ----
  hipMemsetAsync(h0, 0, 2*(size_t)NB*ND*sizeof(float), stream);  // h0 + c0
  for (int ts = 0; ts < NL; ++ts){
    float* hin  = (ts & 1) ? h1 : h0;
    float* hout = (ts & 1) ? h0 : h1;
    k_lstm_step<<<512, 256, 0, stream>>>(hin, hout, c0, xg, w_hh, ts);
  }
  // ts=31 wrote h0 -> final hidden state

  // ---- fused concat + scorer ----
  k_score<<<NB, 256, 0, stream>>>(gsum, gcnt, h0, wm1, bm1, wm2, bm2, (float*)d_out);
}